// Round 6
// baseline (322.609 us; speedup 1.0000x reference)
//
#include <hip/hip_runtime.h>
#include <math.h>

#define N_NODES 100000
#define N_EDGES 1000000
#define IN_DIM  128
#define OUT_DIM 64
#define NEG     0.2f

#define SCAN_BLOCKS 391   // ceil(100000/256)

// ---------------------------------------------------------------------------
// K1: Wh = h @ W^T + b, s_src = Wh.a1, s_tgt = Wh.a2.
// Pure-DS inner loop (R4's s_load version drained lgkmcnt every iter).
// Block = 256 (4 waves) shares one 64-node h tile; lane = node, wave w owns
// dims [16w,16w+16). h rows padded to 33 float4 -> conflict-free b128; W tile
// reads are wave-uniform-address b128 = broadcast (free).
// ---------------------------------------------------------------------------
__global__ __launch_bounds__(256, 2) void k1_gemm(
    const float* __restrict__ h, const float* __restrict__ W,
    const float* __restrict__ Wb, const float* __restrict__ aw,
    float* __restrict__ Wh, float* __restrict__ s_src, float* __restrict__ s_tgt)
{
    __shared__ float4 hts[64 * 33];   // 33 KB; aliased as tr[64][68] floats later
    __shared__ float4 wts[64 * 32];   // 32 KB: wts[d*32 + k4] = W[d][4k4..]
    __shared__ float  sp[8][64];      // p1 (waves 0..3), p2 (waves 0..3)

    const int tid = threadIdx.x;
    const int n0 = blockIdx.x * 64;

    // stage W: 2048 float4, coalesced global, stride-1 LDS writes
    {
        const float4* W4 = (const float4*)W;
#pragma unroll
        for (int it = 0; it < 8; ++it) {
            int i = tid + 256 * it;
            wts[i] = W4[i];
        }
    }
    // stage h: 64 rows x 32 float4, row stride 33
    {
        const float4* h4 = (const float4*)h;
#pragma unroll
        for (int it = 0; it < 8; ++it) {
            int i = tid + 256 * it;
            int n = i >> 5, k4 = i & 31;
            float4 v = make_float4(0.f, 0.f, 0.f, 0.f);
            if (n0 + n < N_NODES) v = h4[(size_t)(n0 + n) * 32 + k4];
            hts[n * 33 + k4] = v;
        }
    }
    __syncthreads();

    const int lane = tid & 63;
    const int w = tid >> 6;             // 0..3
    const int d0 = w * 16;
    const float4* hrow = &hts[lane * 33];
    const float4* wb = &wts[d0 * 32];

    float acc[16];
#pragma unroll
    for (int dd = 0; dd < 16; ++dd) acc[dd] = 0.f;

#pragma unroll 2
    for (int k4 = 0; k4 < 32; ++k4) {
        float4 hv = hrow[k4];
#pragma unroll
        for (int dd = 0; dd < 16; ++dd) {
            float4 wv = wb[dd * 32 + k4];     // uniform addr -> LDS broadcast
            acc[dd] = fmaf(wv.x, hv.x, acc[dd]);
            acc[dd] = fmaf(wv.y, hv.y, acc[dd]);
            acc[dd] = fmaf(wv.z, hv.z, acc[dd]);
            acc[dd] = fmaf(wv.w, hv.w, acc[dd]);
        }
    }

    // bias + score partials (lane = node, 16 dims each)
    float p1 = 0.f, p2 = 0.f;
#pragma unroll
    for (int dd = 0; dd < 16; ++dd) {
        float v = acc[dd] + Wb[d0 + dd];
        acc[dd] = v;
        p1 = fmaf(v, aw[d0 + dd], p1);
        p2 = fmaf(v, aw[OUT_DIM + d0 + dd], p2);
    }
    sp[w][lane] = p1;
    sp[4 + w][lane] = p2;
    __syncthreads();                   // hts reads done; safe to alias below

    // transpose Wh tile through LDS (row stride 68 floats)
    float* tr = (float*)hts;
#pragma unroll
    for (int dd = 0; dd < 16; ++dd)
        tr[lane * 68 + d0 + dd] = acc[dd];
    __syncthreads();

    // coalesced Wh store: 1024 float4, 4 per thread
#pragma unroll
    for (int j = 0; j < 4; ++j) {
        int g = tid + 256 * j;         // 0..1023
        int n = g >> 4, d4 = g & 15;
        if (n0 + n < N_NODES) {
            float4 v = *(const float4*)&tr[n * 68 + d4 * 4];
            ((float4*)Wh)[(size_t)(n0 + n) * 16 + d4] = v;
        }
    }
    // score stores (coalesced)
    if (tid < 64) {
        int n = n0 + tid;
        if (n < N_NODES)
            s_src[n] = sp[0][tid] + sp[1][tid] + sp[2][tid] + sp[3][tid];
    } else if (tid < 128) {
        int n = n0 + tid - 64;
        if (n < N_NODES)
            s_tgt[n] = sp[4][tid - 64] + sp[5][tid - 64] +
                       sp[6][tid - 64] + sp[7][tid - 64];
    }
}

// ---------------------------------------------------------------------------
// K2 (fused): one edge pass computing degree histogram + ex = exp(leaky(logit))
// (stored linearly, coalesced) + global sum. No max-subtraction: logits are
// bounded (|l| ~ 12), exp can't overflow fp32, softmax is shift-invariant.
// ---------------------------------------------------------------------------
__global__ __launch_bounds__(256) void k2_fused(
    const int* __restrict__ ei, const float* __restrict__ s_src,
    const float* __restrict__ s_tgt, const float* __restrict__ ab,
    unsigned* __restrict__ deg, float* __restrict__ exv,
    float* __restrict__ gsum)
{
    const float ab0 = ab[0];
    float lsum = 0.f;
    const int stride = gridDim.x * blockDim.x;
    for (int e = blockIdx.x * blockDim.x + threadIdx.x; e < N_EDGES; e += stride) {
        int s = ei[e], t = ei[N_EDGES + e];
        float x = s_src[s] + s_tgt[t] + ab0;
        float l = x > 0.f ? x : NEG * x;
        float ex = __expf(l);
        exv[e] = ex;
        lsum += ex;
        atomicAdd(&deg[t], 1u);
    }
#pragma unroll
    for (int off = 32; off; off >>= 1) lsum += __shfl_xor(lsum, off);
    __shared__ float ssum[4];
    if ((threadIdx.x & 63) == 0) ssum[threadIdx.x >> 6] = lsum;
    __syncthreads();
    if (threadIdx.x == 0)
        atomicAdd(gsum, ssum[0] + ssum[1] + ssum[2] + ssum[3]);
}

// ---------------------------------------------------------------------------
// Scan (3 kernels): exclusive prefix sum of deg[100000] -> row[], cursor[]
// ---------------------------------------------------------------------------
__global__ __launch_bounds__(256) void k_scan1(
    const unsigned* __restrict__ deg, unsigned* __restrict__ psum)
{
    const int i = blockIdx.x * 256 + threadIdx.x;
    unsigned v = (i < N_NODES) ? deg[i] : 0u;
    unsigned w = v;
#pragma unroll
    for (int off = 32; off; off >>= 1) w += __shfl_xor(w, off);
    __shared__ unsigned ss[4];
    if ((threadIdx.x & 63) == 0) ss[threadIdx.x >> 6] = w;
    __syncthreads();
    if (threadIdx.x == 0) psum[blockIdx.x] = ss[0] + ss[1] + ss[2] + ss[3];
}

__global__ __launch_bounds__(512) void k_scan2(
    const unsigned* __restrict__ psum, unsigned* __restrict__ poff)
{
    __shared__ unsigned sc[512];
    const int t = threadIdx.x;
    unsigned v = (t < SCAN_BLOCKS) ? psum[t] : 0u;
    sc[t] = v;
    __syncthreads();
    for (int off = 1; off < 512; off <<= 1) {
        unsigned u = (t >= off) ? sc[t - off] : 0u;
        __syncthreads();
        sc[t] += u;
        __syncthreads();
    }
    if (t < SCAN_BLOCKS) poff[t] = sc[t] - v;   // exclusive
}

__global__ __launch_bounds__(256) void k_scan3(
    const unsigned* __restrict__ deg, const unsigned* __restrict__ poff,
    unsigned* __restrict__ row, unsigned* __restrict__ cursor)
{
    __shared__ unsigned sc[256];
    const int t = threadIdx.x;
    const int i = blockIdx.x * 256 + t;
    unsigned v = (i < N_NODES) ? deg[i] : 0u;
    sc[t] = v;
    __syncthreads();
    for (int off = 1; off < 256; off <<= 1) {
        unsigned u = (t >= off) ? sc[t - off] : 0u;
        __syncthreads();
        sc[t] += u;
        __syncthreads();
    }
    unsigned r = poff[blockIdx.x] + sc[t] - v;   // exclusive
    if (i < N_NODES) { row[i] = r; cursor[i] = r; }
    if (i == 0) row[N_NODES] = N_EDGES;
}

// ---------------------------------------------------------------------------
// K3: bin fill only — coalesced reads of ei/exv, cursor-scatter of int2.
// ---------------------------------------------------------------------------
__global__ __launch_bounds__(256) void k3_fill(
    const int* __restrict__ ei, const float* __restrict__ exv,
    unsigned* __restrict__ cursor, int2* __restrict__ bin)
{
    const int stride = gridDim.x * blockDim.x;
    for (int e = blockIdx.x * blockDim.x + threadIdx.x; e < N_EDGES; e += stride) {
        int t = ei[N_EDGES + e];
        unsigned pos = atomicAdd(&cursor[t], 1u);
        bin[pos] = make_int2(ei[e], __float_as_int(exv[e]));
    }
}

// ---------------------------------------------------------------------------
// K4: gather — wave per tgt node, lane = dim. Bin chunk loaded coalesced
// (8B/lane), entries broadcast via shfl. 4-way ILP: 4 independent gathers +
// 4 accumulators per step (R5 was a serial dependent chain: VALUBusy 25%,
// ~300cyc latency x deg sequential loads per wave). One plain store per
// node, leaky fused, no atomics.
// ---------------------------------------------------------------------------
__global__ __launch_bounds__(256) void k_gather(
    const unsigned* __restrict__ row, const int2* __restrict__ bin,
    const float* __restrict__ gsum, const float* __restrict__ Wh,
    float* __restrict__ out)
{
    const int lane = threadIdx.x & 63;
    const int t = blockIdx.x * 4 + (threadIdx.x >> 6);
    if (t >= N_NODES) return;
    const unsigned beg = row[t], end = row[t + 1];
    float a0 = 0.f, a1 = 0.f, a2 = 0.f, a3 = 0.f;
    for (unsigned base = beg; base < end; base += 64) {
        const int cnt = (int)min(64u, end - base);
        int2 p = make_int2(0, 0);
        if (lane < cnt) p = bin[base + lane];      // coalesced 8B/lane
        int j = 0;
        for (; j + 4 <= cnt; j += 4) {
            int   s0 = __shfl(p.x, j);     float w0 = __int_as_float(__shfl(p.y, j));
            int   s1 = __shfl(p.x, j + 1); float w1 = __int_as_float(__shfl(p.y, j + 1));
            int   s2 = __shfl(p.x, j + 2); float w2 = __int_as_float(__shfl(p.y, j + 2));
            int   s3 = __shfl(p.x, j + 3); float w3 = __int_as_float(__shfl(p.y, j + 3));
            float v0 = Wh[(size_t)s0 * OUT_DIM + lane];
            float v1 = Wh[(size_t)s1 * OUT_DIM + lane];
            float v2 = Wh[(size_t)s2 * OUT_DIM + lane];
            float v3 = Wh[(size_t)s3 * OUT_DIM + lane];
            a0 = fmaf(w0, v0, a0);
            a1 = fmaf(w1, v1, a1);
            a2 = fmaf(w2, v2, a2);
            a3 = fmaf(w3, v3, a3);
        }
        for (; j < cnt; ++j) {
            int   s = __shfl(p.x, j);
            float w = __int_as_float(__shfl(p.y, j));
            a0 = fmaf(w, Wh[(size_t)s * OUT_DIM + lane], a0);
        }
    }
    float v = ((a0 + a1) + (a2 + a3)) * (1.0f / gsum[0]);
    out[(size_t)t * OUT_DIM + lane] = v > 0.f ? v : NEG * v;
}

extern "C" void kernel_launch(void* const* d_in, const int* in_sizes, int n_in,
                              void* d_out, int out_size, void* d_ws, size_t ws_size,
                              hipStream_t stream)
{
    const float* h  = (const float*)d_in[0];
    const float* W  = (const float*)d_in[1];
    const float* Wb = (const float*)d_in[2];
    const float* aw = (const float*)d_in[3];
    const float* ab = (const float*)d_in[4];
    const int*   ei = (const int*)d_in[5];

    // ws layout: Wh[N*64] f32 | s_src[N] | s_tgt[N] | deg[N] u32 | row[N+1] u32
    //          | cursor[N] u32 | psum[512] | poff[512] | bin[E] int2
    //          | exv[E] f32 | gsum f32
    float* ws      = (float*)d_ws;
    float* Wh      = ws;
    float* s_src   = Wh + (size_t)N_NODES * OUT_DIM;
    float* s_tgt   = s_src + N_NODES;
    unsigned* deg    = (unsigned*)(s_tgt + N_NODES);
    unsigned* row    = deg + N_NODES;
    unsigned* cursor = row + N_NODES + 1;
    unsigned* psum   = cursor + N_NODES;
    unsigned* poff   = psum + 512;
    int2*     bin    = (int2*)(poff + 512);
    float*    exv    = (float*)(bin + N_EDGES);
    float*    gsum   = exv + N_EDGES;

    float* out = (float*)d_out;

    hipMemsetAsync((void*)deg, 0, N_NODES * sizeof(unsigned), stream);
    hipMemsetAsync((void*)gsum, 0, 4, stream);

    k1_gemm<<<(N_NODES + 63) / 64, 256, 0, stream>>>(h, W, Wb, aw, Wh, s_src, s_tgt);
    k2_fused<<<1024, 256, 0, stream>>>(ei, s_src, s_tgt, ab, deg, exv, gsum);
    k_scan1<<<SCAN_BLOCKS, 256, 0, stream>>>(deg, psum);
    k_scan2<<<1, 512, 0, stream>>>(psum, poff);
    k_scan3<<<SCAN_BLOCKS, 256, 0, stream>>>(deg, poff, row, cursor);
    k3_fill<<<1024, 256, 0, stream>>>(ei, exv, cursor, bin);
    k_gather<<<(N_NODES + 3) / 4, 256, 0, stream>>>(row, bin, gsum, Wh, out);
}

// Round 7
// 283.129 us; speedup vs baseline: 1.1394x; 1.1394x over previous
//
#include <hip/hip_runtime.h>
#include <math.h>

#define N_NODES 100000
#define N_EDGES 1000000
#define IN_DIM  128
#define OUT_DIM 64
#define NEG     0.2f

#define SCAN_BLOCKS 391   // ceil(100000/256)
#define EDGE_BLOCKS 3907  // ceil(1000000/256): one edge per thread

// ---------------------------------------------------------------------------
// K1: Wh = h @ W^T + b, s_src = Wh.a1, s_tgt = Wh.a2.
// Pure-DS inner loop (R4's s_load version drained lgkmcnt every iter).
// Block = 256 (4 waves) shares one 64-node h tile; lane = node, wave w owns
// dims [16w,16w+16). h rows padded to 33 float4 -> conflict-free b128; W tile
// reads are wave-uniform-address b128 = broadcast (free).
// ---------------------------------------------------------------------------
__global__ __launch_bounds__(256, 2) void k1_gemm(
    const float* __restrict__ h, const float* __restrict__ W,
    const float* __restrict__ Wb, const float* __restrict__ aw,
    float* __restrict__ Wh, float* __restrict__ s_src, float* __restrict__ s_tgt)
{
    __shared__ float4 hts[64 * 33];   // 33 KB; aliased as tr[64][68] floats later
    __shared__ float4 wts[64 * 32];   // 32 KB: wts[d*32 + k4] = W[d][4k4..]
    __shared__ float  sp[8][64];      // p1 (waves 0..3), p2 (waves 0..3)

    const int tid = threadIdx.x;
    const int n0 = blockIdx.x * 64;

    // stage W: 2048 float4, coalesced global, stride-1 LDS writes
    {
        const float4* W4 = (const float4*)W;
#pragma unroll
        for (int it = 0; it < 8; ++it) {
            int i = tid + 256 * it;
            wts[i] = W4[i];
        }
    }
    // stage h: 64 rows x 32 float4, row stride 33
    {
        const float4* h4 = (const float4*)h;
#pragma unroll
        for (int it = 0; it < 8; ++it) {
            int i = tid + 256 * it;
            int n = i >> 5, k4 = i & 31;
            float4 v = make_float4(0.f, 0.f, 0.f, 0.f);
            if (n0 + n < N_NODES) v = h4[(size_t)(n0 + n) * 32 + k4];
            hts[n * 33 + k4] = v;
        }
    }
    __syncthreads();

    const int lane = tid & 63;
    const int w = tid >> 6;             // 0..3
    const int d0 = w * 16;
    const float4* hrow = &hts[lane * 33];
    const float4* wb = &wts[d0 * 32];

    float acc[16];
#pragma unroll
    for (int dd = 0; dd < 16; ++dd) acc[dd] = 0.f;

#pragma unroll 2
    for (int k4 = 0; k4 < 32; ++k4) {
        float4 hv = hrow[k4];
#pragma unroll
        for (int dd = 0; dd < 16; ++dd) {
            float4 wv = wb[dd * 32 + k4];     // uniform addr -> LDS broadcast
            acc[dd] = fmaf(wv.x, hv.x, acc[dd]);
            acc[dd] = fmaf(wv.y, hv.y, acc[dd]);
            acc[dd] = fmaf(wv.z, hv.z, acc[dd]);
            acc[dd] = fmaf(wv.w, hv.w, acc[dd]);
        }
    }

    // bias + score partials (lane = node, 16 dims each)
    float p1 = 0.f, p2 = 0.f;
#pragma unroll
    for (int dd = 0; dd < 16; ++dd) {
        float v = acc[dd] + Wb[d0 + dd];
        acc[dd] = v;
        p1 = fmaf(v, aw[d0 + dd], p1);
        p2 = fmaf(v, aw[OUT_DIM + d0 + dd], p2);
    }
    sp[w][lane] = p1;
    sp[4 + w][lane] = p2;
    __syncthreads();                   // hts reads done; safe to alias below

    // transpose Wh tile through LDS (row stride 68 floats)
    float* tr = (float*)hts;
#pragma unroll
    for (int dd = 0; dd < 16; ++dd)
        tr[lane * 68 + d0 + dd] = acc[dd];
    __syncthreads();

    // coalesced Wh store: 1024 float4, 4 per thread
#pragma unroll
    for (int j = 0; j < 4; ++j) {
        int g = tid + 256 * j;         // 0..1023
        int n = g >> 4, d4 = g & 15;
        if (n0 + n < N_NODES) {
            float4 v = *(const float4*)&tr[n * 68 + d4 * 4];
            ((float4*)Wh)[(size_t)(n0 + n) * 16 + d4] = v;
        }
    }
    // score stores (coalesced)
    if (tid < 64) {
        int n = n0 + tid;
        if (n < N_NODES)
            s_src[n] = sp[0][tid] + sp[1][tid] + sp[2][tid] + sp[3][tid];
    } else if (tid < 128) {
        int n = n0 + tid - 64;
        if (n < N_NODES)
            s_tgt[n] = sp[4][tid - 64] + sp[5][tid - 64] +
                       sp[6][tid - 64] + sp[7][tid - 64];
    }
}

// ---------------------------------------------------------------------------
// K2 (fused): one edge pass: deg histogram (capturing the returned RANK —
// this edge's slot within its target, free CSR position), ex = exp(leaky(l))
// stored linearly, global sum. One edge per thread for max TLP.
// No max-subtraction: logits bounded (~|12|), exp can't overflow fp32,
// softmax is shift-invariant.
// ---------------------------------------------------------------------------
__global__ __launch_bounds__(256) void k2_fused(
    const int* __restrict__ ei, const float* __restrict__ s_src,
    const float* __restrict__ s_tgt, const float* __restrict__ ab,
    unsigned* __restrict__ deg, unsigned* __restrict__ rank,
    float* __restrict__ exv, float* __restrict__ gsum)
{
    const float ab0 = ab[0];
    float lsum = 0.f;
    const int e = blockIdx.x * blockDim.x + threadIdx.x;
    if (e < N_EDGES) {
        int s = ei[e], t = ei[N_EDGES + e];
        float x = s_src[s] + s_tgt[t] + ab0;
        float l = x > 0.f ? x : NEG * x;
        float ex = __expf(l);
        exv[e] = ex;
        lsum = ex;
        rank[e] = atomicAdd(&deg[t], 1u);   // returned old count = CSR rank
    }
#pragma unroll
    for (int off = 32; off; off >>= 1) lsum += __shfl_xor(lsum, off);
    __shared__ float ssum[4];
    if ((threadIdx.x & 63) == 0) ssum[threadIdx.x >> 6] = lsum;
    __syncthreads();
    if (threadIdx.x == 0)
        atomicAdd(gsum, ssum[0] + ssum[1] + ssum[2] + ssum[3]);
}

// ---------------------------------------------------------------------------
// Scan (3 kernels): exclusive prefix sum of deg[100000] -> row[]
// ---------------------------------------------------------------------------
__global__ __launch_bounds__(256) void k_scan1(
    const unsigned* __restrict__ deg, unsigned* __restrict__ psum)
{
    const int i = blockIdx.x * 256 + threadIdx.x;
    unsigned v = (i < N_NODES) ? deg[i] : 0u;
    unsigned w = v;
#pragma unroll
    for (int off = 32; off; off >>= 1) w += __shfl_xor(w, off);
    __shared__ unsigned ss[4];
    if ((threadIdx.x & 63) == 0) ss[threadIdx.x >> 6] = w;
    __syncthreads();
    if (threadIdx.x == 0) psum[blockIdx.x] = ss[0] + ss[1] + ss[2] + ss[3];
}

__global__ __launch_bounds__(512) void k_scan2(
    const unsigned* __restrict__ psum, unsigned* __restrict__ poff)
{
    __shared__ unsigned sc[512];
    const int t = threadIdx.x;
    unsigned v = (t < SCAN_BLOCKS) ? psum[t] : 0u;
    sc[t] = v;
    __syncthreads();
    for (int off = 1; off < 512; off <<= 1) {
        unsigned u = (t >= off) ? sc[t - off] : 0u;
        __syncthreads();
        sc[t] += u;
        __syncthreads();
    }
    if (t < SCAN_BLOCKS) poff[t] = sc[t] - v;   // exclusive
}

__global__ __launch_bounds__(256) void k_scan3(
    const unsigned* __restrict__ deg, const unsigned* __restrict__ poff,
    unsigned* __restrict__ row)
{
    __shared__ unsigned sc[256];
    const int t = threadIdx.x;
    const int i = blockIdx.x * 256 + t;
    unsigned v = (i < N_NODES) ? deg[i] : 0u;
    sc[t] = v;
    __syncthreads();
    for (int off = 1; off < 256; off <<= 1) {
        unsigned u = (t >= off) ? sc[t - off] : 0u;
        __syncthreads();
        sc[t] += u;
        __syncthreads();
    }
    unsigned r = poff[blockIdx.x] + sc[t] - v;   // exclusive
    if (i < N_NODES) row[i] = r;
    if (i == 0) row[N_NODES] = N_EDGES;
}

// ---------------------------------------------------------------------------
// K3: bin fill, NO atomics (R6's 82µs was the atomicAdd return-value chain:
// VALUBusy 0.3%, occ 38%). pos = row[t] + rank[e]; the scatter write has no
// value dependency -> fire-and-forget. One edge per thread.
// ---------------------------------------------------------------------------
__global__ __launch_bounds__(256) void k3_fill(
    const int* __restrict__ ei, const float* __restrict__ exv,
    const unsigned* __restrict__ rank, const unsigned* __restrict__ row,
    int2* __restrict__ bin)
{
    const int e = blockIdx.x * blockDim.x + threadIdx.x;
    if (e >= N_EDGES) return;
    int t = ei[N_EDGES + e];
    unsigned pos = row[t] + rank[e];
    bin[pos] = make_int2(ei[e], __float_as_int(exv[e]));
}

// ---------------------------------------------------------------------------
// K4: gather — wave per tgt node, lane = dim. Bin chunk loaded coalesced
// (8B/lane), entries broadcast via shfl. 4-way ILP: 4 independent gathers +
// 4 accumulators per step. One plain store per node, leaky fused, no atomics.
// ---------------------------------------------------------------------------
__global__ __launch_bounds__(256) void k_gather(
    const unsigned* __restrict__ row, const int2* __restrict__ bin,
    const float* __restrict__ gsum, const float* __restrict__ Wh,
    float* __restrict__ out)
{
    const int lane = threadIdx.x & 63;
    const int t = blockIdx.x * 4 + (threadIdx.x >> 6);
    if (t >= N_NODES) return;
    const unsigned beg = row[t], end = row[t + 1];
    float a0 = 0.f, a1 = 0.f, a2 = 0.f, a3 = 0.f;
    for (unsigned base = beg; base < end; base += 64) {
        const int cnt = (int)min(64u, end - base);
        int2 p = make_int2(0, 0);
        if (lane < cnt) p = bin[base + lane];      // coalesced 8B/lane
        int j = 0;
        for (; j + 4 <= cnt; j += 4) {
            int   s0 = __shfl(p.x, j);     float w0 = __int_as_float(__shfl(p.y, j));
            int   s1 = __shfl(p.x, j + 1); float w1 = __int_as_float(__shfl(p.y, j + 1));
            int   s2 = __shfl(p.x, j + 2); float w2 = __int_as_float(__shfl(p.y, j + 2));
            int   s3 = __shfl(p.x, j + 3); float w3 = __int_as_float(__shfl(p.y, j + 3));
            float v0 = Wh[(size_t)s0 * OUT_DIM + lane];
            float v1 = Wh[(size_t)s1 * OUT_DIM + lane];
            float v2 = Wh[(size_t)s2 * OUT_DIM + lane];
            float v3 = Wh[(size_t)s3 * OUT_DIM + lane];
            a0 = fmaf(w0, v0, a0);
            a1 = fmaf(w1, v1, a1);
            a2 = fmaf(w2, v2, a2);
            a3 = fmaf(w3, v3, a3);
        }
        for (; j < cnt; ++j) {
            int   s = __shfl(p.x, j);
            float w = __int_as_float(__shfl(p.y, j));
            a0 = fmaf(w, Wh[(size_t)s * OUT_DIM + lane], a0);
        }
    }
    float v = ((a0 + a1) + (a2 + a3)) * (1.0f / gsum[0]);
    out[(size_t)t * OUT_DIM + lane] = v > 0.f ? v : NEG * v;
}

extern "C" void kernel_launch(void* const* d_in, const int* in_sizes, int n_in,
                              void* d_out, int out_size, void* d_ws, size_t ws_size,
                              hipStream_t stream)
{
    const float* h  = (const float*)d_in[0];
    const float* W  = (const float*)d_in[1];
    const float* Wb = (const float*)d_in[2];
    const float* aw = (const float*)d_in[3];
    const float* ab = (const float*)d_in[4];
    const int*   ei = (const int*)d_in[5];

    // ws layout: Wh[N*64] f32 | s_src[N] | s_tgt[N] | deg[N] u32 | row[N+1] u32
    //          | psum[512] | poff[512] | bin[E] int2 | exv[E] f32
    //          | rank[E] u32 | gsum f32
    float* ws      = (float*)d_ws;
    float* Wh      = ws;
    float* s_src   = Wh + (size_t)N_NODES * OUT_DIM;
    float* s_tgt   = s_src + N_NODES;
    unsigned* deg    = (unsigned*)(s_tgt + N_NODES);
    unsigned* row    = deg + N_NODES;
    unsigned* psum   = row + N_NODES + 1;
    unsigned* poff   = psum + 512;
    int2*     bin    = (int2*)(poff + 512);
    float*    exv    = (float*)(bin + N_EDGES);
    unsigned* rank   = (unsigned*)(exv + N_EDGES);
    float*    gsum   = (float*)(rank + N_EDGES);

    float* out = (float*)d_out;

    hipMemsetAsync((void*)deg, 0, N_NODES * sizeof(unsigned), stream);
    hipMemsetAsync((void*)gsum, 0, 4, stream);

    k1_gemm<<<(N_NODES + 63) / 64, 256, 0, stream>>>(h, W, Wb, aw, Wh, s_src, s_tgt);
    k2_fused<<<EDGE_BLOCKS, 256, 0, stream>>>(ei, s_src, s_tgt, ab, deg, rank,
                                              exv, gsum);
    k_scan1<<<SCAN_BLOCKS, 256, 0, stream>>>(deg, psum);
    k_scan2<<<1, 512, 0, stream>>>(psum, poff);
    k_scan3<<<SCAN_BLOCKS, 256, 0, stream>>>(deg, poff, row);
    k3_fill<<<EDGE_BLOCKS, 256, 0, stream>>>(ei, exv, rank, row, bin);
    k_gather<<<(N_NODES + 3) / 4, 256, 0, stream>>>(row, bin, gsum, Wh, out);
}

// Round 8
// 258.865 us; speedup vs baseline: 1.2462x; 1.0937x over previous
//
#include <hip/hip_runtime.h>
#include <math.h>

#define N_NODES 100000
#define N_EDGES 1000000
#define IN_DIM  128
#define OUT_DIM 64
#define NEG     0.2f

#define SCAN_BLOCKS 391   // ceil(100000/256)
#define EDGE_BLOCKS 3907  // ceil(1000000/256): one edge per thread

// ---------------------------------------------------------------------------
// K1: Wh = h @ W^T + b, s_src = Wh.a1, s_tgt = Wh.a2.
// Pure-DS inner loop (R4's s_load version drained lgkmcnt every iter).
// Block = 256 (4 waves) shares one 64-node h tile; lane = node, wave w owns
// dims [16w,16w+16). h rows padded to 33 float4 -> conflict-free b128; W tile
// reads are wave-uniform-address b128 = broadcast (free).
// ---------------------------------------------------------------------------
__global__ __launch_bounds__(256, 2) void k1_gemm(
    const float* __restrict__ h, const float* __restrict__ W,
    const float* __restrict__ Wb, const float* __restrict__ aw,
    float* __restrict__ Wh, float* __restrict__ s_src, float* __restrict__ s_tgt)
{
    __shared__ float4 hts[64 * 33];   // 33 KB; aliased as tr[64][68] floats later
    __shared__ float4 wts[64 * 32];   // 32 KB: wts[d*32 + k4] = W[d][4k4..]
    __shared__ float  sp[8][64];      // p1 (waves 0..3), p2 (waves 0..3)

    const int tid = threadIdx.x;
    const int n0 = blockIdx.x * 64;

    // stage W: 2048 float4, coalesced global, stride-1 LDS writes
    {
        const float4* W4 = (const float4*)W;
#pragma unroll
        for (int it = 0; it < 8; ++it) {
            int i = tid + 256 * it;
            wts[i] = W4[i];
        }
    }
    // stage h: 64 rows x 32 float4, row stride 33
    {
        const float4* h4 = (const float4*)h;
#pragma unroll
        for (int it = 0; it < 8; ++it) {
            int i = tid + 256 * it;
            int n = i >> 5, k4 = i & 31;
            float4 v = make_float4(0.f, 0.f, 0.f, 0.f);
            if (n0 + n < N_NODES) v = h4[(size_t)(n0 + n) * 32 + k4];
            hts[n * 33 + k4] = v;
        }
    }
    __syncthreads();

    const int lane = tid & 63;
    const int w = tid >> 6;             // 0..3
    const int d0 = w * 16;
    const float4* hrow = &hts[lane * 33];
    const float4* wb = &wts[d0 * 32];

    float acc[16];
#pragma unroll
    for (int dd = 0; dd < 16; ++dd) acc[dd] = 0.f;

#pragma unroll 2
    for (int k4 = 0; k4 < 32; ++k4) {
        float4 hv = hrow[k4];
#pragma unroll
        for (int dd = 0; dd < 16; ++dd) {
            float4 wv = wb[dd * 32 + k4];     // uniform addr -> LDS broadcast
            acc[dd] = fmaf(wv.x, hv.x, acc[dd]);
            acc[dd] = fmaf(wv.y, hv.y, acc[dd]);
            acc[dd] = fmaf(wv.z, hv.z, acc[dd]);
            acc[dd] = fmaf(wv.w, hv.w, acc[dd]);
        }
    }

    // bias + score partials (lane = node, 16 dims each)
    float p1 = 0.f, p2 = 0.f;
#pragma unroll
    for (int dd = 0; dd < 16; ++dd) {
        float v = acc[dd] + Wb[d0 + dd];
        acc[dd] = v;
        p1 = fmaf(v, aw[d0 + dd], p1);
        p2 = fmaf(v, aw[OUT_DIM + d0 + dd], p2);
    }
    sp[w][lane] = p1;
    sp[4 + w][lane] = p2;
    __syncthreads();                   // hts reads done; safe to alias below

    // transpose Wh tile through LDS (row stride 68 floats)
    float* tr = (float*)hts;
#pragma unroll
    for (int dd = 0; dd < 16; ++dd)
        tr[lane * 68 + d0 + dd] = acc[dd];
    __syncthreads();

    // coalesced Wh store: 1024 float4, 4 per thread
#pragma unroll
    for (int j = 0; j < 4; ++j) {
        int g = tid + 256 * j;         // 0..1023
        int n = g >> 4, d4 = g & 15;
        if (n0 + n < N_NODES) {
            float4 v = *(const float4*)&tr[n * 68 + d4 * 4];
            ((float4*)Wh)[(size_t)(n0 + n) * 16 + d4] = v;
        }
    }
    // score stores (coalesced)
    if (tid < 64) {
        int n = n0 + tid;
        if (n < N_NODES)
            s_src[n] = sp[0][tid] + sp[1][tid] + sp[2][tid] + sp[3][tid];
    } else if (tid < 128) {
        int n = n0 + tid - 64;
        if (n < N_NODES)
            s_tgt[n] = sp[4][tid - 64] + sp[5][tid - 64] +
                       sp[6][tid - 64] + sp[7][tid - 64];
    }
}

// ---------------------------------------------------------------------------
// K2 (fused): one edge pass: deg histogram (capturing the returned RANK =
// CSR slot), ex = exp(leaky(l)) stored linearly, block-partial sums to
// bsum[] (plain store — R7's single-address atomicAdd(gsum) serialized 3907
// RMWs and stalled block retirement: occ 59% / VALU 2% / 70µs).
// No max-subtraction: logits bounded (~|12|), exp can't overflow fp32,
// softmax is shift-invariant.
// ---------------------------------------------------------------------------
__global__ __launch_bounds__(256) void k2_fused(
    const int* __restrict__ ei, const float* __restrict__ s_src,
    const float* __restrict__ s_tgt, const float* __restrict__ ab,
    unsigned* __restrict__ deg, unsigned* __restrict__ rank,
    float* __restrict__ exv, float* __restrict__ bsum)
{
    const float ab0 = ab[0];
    float lsum = 0.f;
    const int e = blockIdx.x * blockDim.x + threadIdx.x;
    if (e < N_EDGES) {
        int s = ei[e], t = ei[N_EDGES + e];
        float x = s_src[s] + s_tgt[t] + ab0;
        float l = x > 0.f ? x : NEG * x;
        float ex = __expf(l);
        exv[e] = ex;
        lsum = ex;
        rank[e] = atomicAdd(&deg[t], 1u);   // returned old count = CSR rank
    }
#pragma unroll
    for (int off = 32; off; off >>= 1) lsum += __shfl_xor(lsum, off);
    __shared__ float ssum[4];
    if ((threadIdx.x & 63) == 0) ssum[threadIdx.x >> 6] = lsum;
    __syncthreads();
    if (threadIdx.x == 0)
        bsum[blockIdx.x] = ssum[0] + ssum[1] + ssum[2] + ssum[3];
}

// ---------------------------------------------------------------------------
// Scan (3 kernels): exclusive prefix sum of deg[100000] -> row[].
// k_scan2 additionally reduces bsum[] -> gsum (free ride on the single-block
// dispatch; removes the serialized gsum atomic entirely).
// ---------------------------------------------------------------------------
__global__ __launch_bounds__(256) void k_scan1(
    const unsigned* __restrict__ deg, unsigned* __restrict__ psum)
{
    const int i = blockIdx.x * 256 + threadIdx.x;
    unsigned v = (i < N_NODES) ? deg[i] : 0u;
    unsigned w = v;
#pragma unroll
    for (int off = 32; off; off >>= 1) w += __shfl_xor(w, off);
    __shared__ unsigned ss[4];
    if ((threadIdx.x & 63) == 0) ss[threadIdx.x >> 6] = w;
    __syncthreads();
    if (threadIdx.x == 0) psum[blockIdx.x] = ss[0] + ss[1] + ss[2] + ss[3];
}

__global__ __launch_bounds__(512) void k_scan2(
    const unsigned* __restrict__ psum, unsigned* __restrict__ poff,
    const float* __restrict__ bsum, float* __restrict__ gsum)
{
    __shared__ unsigned sc[512];
    __shared__ float    sf[8];
    const int t = threadIdx.x;

    // part 1: exclusive scan of psum[SCAN_BLOCKS]
    unsigned v = (t < SCAN_BLOCKS) ? psum[t] : 0u;
    sc[t] = v;
    __syncthreads();
    for (int off = 1; off < 512; off <<= 1) {
        unsigned u = (t >= off) ? sc[t - off] : 0u;
        __syncthreads();
        sc[t] += u;
        __syncthreads();
    }
    if (t < SCAN_BLOCKS) poff[t] = sc[t] - v;   // exclusive

    // part 2: reduce bsum[EDGE_BLOCKS] -> gsum
    float s = 0.f;
    for (int i = t; i < EDGE_BLOCKS; i += 512) s += bsum[i];
#pragma unroll
    for (int off = 32; off; off >>= 1) s += __shfl_xor(s, off);
    if ((t & 63) == 0) sf[t >> 6] = s;
    __syncthreads();
    if (t == 0) {
        float tot = 0.f;
#pragma unroll
        for (int i = 0; i < 8; ++i) tot += sf[i];
        gsum[0] = tot;
    }
}

__global__ __launch_bounds__(256) void k_scan3(
    const unsigned* __restrict__ deg, const unsigned* __restrict__ poff,
    unsigned* __restrict__ row)
{
    __shared__ unsigned sc[256];
    const int t = threadIdx.x;
    const int i = blockIdx.x * 256 + t;
    unsigned v = (i < N_NODES) ? deg[i] : 0u;
    sc[t] = v;
    __syncthreads();
    for (int off = 1; off < 256; off <<= 1) {
        unsigned u = (t >= off) ? sc[t - off] : 0u;
        __syncthreads();
        sc[t] += u;
        __syncthreads();
    }
    unsigned r = poff[blockIdx.x] + sc[t] - v;   // exclusive
    if (i < N_NODES) row[i] = r;
    if (i == 0) row[N_NODES] = N_EDGES;
}

// ---------------------------------------------------------------------------
// K3: bin fill, NO atomics: pos = row[t] + rank[e]; scatter write is
// fire-and-forget. One edge per thread.
// ---------------------------------------------------------------------------
__global__ __launch_bounds__(256) void k3_fill(
    const int* __restrict__ ei, const float* __restrict__ exv,
    const unsigned* __restrict__ rank, const unsigned* __restrict__ row,
    int2* __restrict__ bin)
{
    const int e = blockIdx.x * blockDim.x + threadIdx.x;
    if (e >= N_EDGES) return;
    int t = ei[N_EDGES + e];
    unsigned pos = row[t] + rank[e];
    bin[pos] = make_int2(ei[e], __float_as_int(exv[e]));
}

// ---------------------------------------------------------------------------
// K4: gather — wave per tgt node, lane = dim. Bin chunk loaded coalesced
// (8B/lane), entries broadcast via shfl. 4-way ILP: 4 independent gathers +
// 4 accumulators per step. One plain store per node, leaky fused, no atomics.
// ---------------------------------------------------------------------------
__global__ __launch_bounds__(256) void k_gather(
    const unsigned* __restrict__ row, const int2* __restrict__ bin,
    const float* __restrict__ gsum, const float* __restrict__ Wh,
    float* __restrict__ out)
{
    const int lane = threadIdx.x & 63;
    const int t = blockIdx.x * 4 + (threadIdx.x >> 6);
    if (t >= N_NODES) return;
    const unsigned beg = row[t], end = row[t + 1];
    float a0 = 0.f, a1 = 0.f, a2 = 0.f, a3 = 0.f;
    for (unsigned base = beg; base < end; base += 64) {
        const int cnt = (int)min(64u, end - base);
        int2 p = make_int2(0, 0);
        if (lane < cnt) p = bin[base + lane];      // coalesced 8B/lane
        int j = 0;
        for (; j + 4 <= cnt; j += 4) {
            int   s0 = __shfl(p.x, j);     float w0 = __int_as_float(__shfl(p.y, j));
            int   s1 = __shfl(p.x, j + 1); float w1 = __int_as_float(__shfl(p.y, j + 1));
            int   s2 = __shfl(p.x, j + 2); float w2 = __int_as_float(__shfl(p.y, j + 2));
            int   s3 = __shfl(p.x, j + 3); float w3 = __int_as_float(__shfl(p.y, j + 3));
            float v0 = Wh[(size_t)s0 * OUT_DIM + lane];
            float v1 = Wh[(size_t)s1 * OUT_DIM + lane];
            float v2 = Wh[(size_t)s2 * OUT_DIM + lane];
            float v3 = Wh[(size_t)s3 * OUT_DIM + lane];
            a0 = fmaf(w0, v0, a0);
            a1 = fmaf(w1, v1, a1);
            a2 = fmaf(w2, v2, a2);
            a3 = fmaf(w3, v3, a3);
        }
        for (; j < cnt; ++j) {
            int   s = __shfl(p.x, j);
            float w = __int_as_float(__shfl(p.y, j));
            a0 = fmaf(w, Wh[(size_t)s * OUT_DIM + lane], a0);
        }
    }
    float v = ((a0 + a1) + (a2 + a3)) * (1.0f / gsum[0]);
    out[(size_t)t * OUT_DIM + lane] = v > 0.f ? v : NEG * v;
}

extern "C" void kernel_launch(void* const* d_in, const int* in_sizes, int n_in,
                              void* d_out, int out_size, void* d_ws, size_t ws_size,
                              hipStream_t stream)
{
    const float* h  = (const float*)d_in[0];
    const float* W  = (const float*)d_in[1];
    const float* Wb = (const float*)d_in[2];
    const float* aw = (const float*)d_in[3];
    const float* ab = (const float*)d_in[4];
    const int*   ei = (const int*)d_in[5];

    // ws layout: Wh[N*64] f32 | s_src[N] | s_tgt[N] | deg[N] u32 | row[N+1] u32
    //          | psum[512] | poff[512] | bin[E] int2 | exv[E] f32
    //          | rank[E] u32 | bsum[4096] f32 | gsum f32
    float* ws      = (float*)d_ws;
    float* Wh      = ws;
    float* s_src   = Wh + (size_t)N_NODES * OUT_DIM;
    float* s_tgt   = s_src + N_NODES;
    unsigned* deg    = (unsigned*)(s_tgt + N_NODES);
    unsigned* row    = deg + N_NODES;
    unsigned* psum   = row + N_NODES + 1;
    unsigned* poff   = psum + 512;
    int2*     bin    = (int2*)(poff + 512);
    float*    exv    = (float*)(bin + N_EDGES);
    unsigned* rank   = (unsigned*)(exv + N_EDGES);
    float*    bsum   = (float*)(rank + N_EDGES);
    float*    gsum   = bsum + 4096;

    float* out = (float*)d_out;

    hipMemsetAsync((void*)deg, 0, N_NODES * sizeof(unsigned), stream);

    k1_gemm<<<(N_NODES + 63) / 64, 256, 0, stream>>>(h, W, Wb, aw, Wh, s_src, s_tgt);
    k2_fused<<<EDGE_BLOCKS, 256, 0, stream>>>(ei, s_src, s_tgt, ab, deg, rank,
                                              exv, bsum);
    k_scan1<<<SCAN_BLOCKS, 256, 0, stream>>>(deg, psum);
    k_scan2<<<1, 512, 0, stream>>>(psum, poff, bsum, gsum);
    k_scan3<<<SCAN_BLOCKS, 256, 0, stream>>>(deg, poff, row);
    k3_fill<<<EDGE_BLOCKS, 256, 0, stream>>>(ei, exv, rank, row, bin);
    k_gather<<<(N_NODES + 3) / 4, 256, 0, stream>>>(row, bin, gsum, Wh, out);
}